// Round 7
// baseline (235.838 us; speedup 1.0000x reference)
//
#include <hip/hip_runtime.h>
#include <cstdint>

typedef unsigned short u16;
typedef __attribute__((ext_vector_type(8))) short bf16x8;   // 8 bf16 = 4 VGPRs
typedef __attribute__((ext_vector_type(4))) short bf16x4;   // 4 bf16 = 2 VGPRs
typedef __attribute__((ext_vector_type(4))) float f32x4;

#define S_LEN 2048
#define HDIM  1024
#define NHEAD 16

__device__ __forceinline__ float bf2f(u16 u){ return __uint_as_float(((uint32_t)u) << 16); }
__device__ __forceinline__ u16 f2bf(float f){
  uint32_t x = __float_as_uint(f);
  return (u16)((x + 0x7fffu + ((x >> 16) & 1u)) >> 16);   // RNE
}

// 2^x via the native v_exp_f32 (gfx950: v_exp_f32 computes 2^S0)
__device__ __forceinline__ float exp2_fast(float x){
  float r; asm("v_exp_f32 %0, %1" : "=v"(r) : "v"(x)); return r;
}

// async global->LDS 16B (m97 idiom). LDS dest is wave-uniform base + lane*16.
__device__ __forceinline__ void gload_lds16(const void* g, void* l){
  __builtin_amdgcn_global_load_lds((const __attribute__((address_space(1))) void*)g,
                                   (__attribute__((address_space(3))) void*)l, 16, 0, 0);
}

// ---------------- merged preprocessing: cvt3 (blocks 0..6143) + weight transpose (6144..7167) ----
// cvt: f32->bf16 for q,k,v (8 elems/thread). tr: wt[n][k] = w[k][n] for the 4 weights.
__global__ __launch_bounds__(256) void k_pre(const float* __restrict__ q, const float* __restrict__ k,
                                             const float* __restrict__ v, u16* __restrict__ oq,
                                             u16* __restrict__ ok, u16* __restrict__ ov,
                                             const float* __restrict__ w0, const float* __restrict__ w1,
                                             const float* __restrict__ w2, const float* __restrict__ w3,
                                             u16* __restrict__ o0, u16* __restrict__ o1,
                                             u16* __restrict__ o2, u16* __restrict__ o3)
{
  __shared__ float t[64][65];
  int bid = blockIdx.x, tid = threadIdx.x;
  if (bid < 6144) {
    int z = bid / 2048, xi = bid - z * 2048;
    const float* in = z == 0 ? q : (z == 1 ? k : v);
    u16* out = z == 0 ? oq : (z == 1 ? ok : ov);
    int i = xi * 256 + tid;
    float4 f0 = *(const float4*)&in[(size_t)i * 8];
    float4 f1 = *(const float4*)&in[(size_t)i * 8 + 4];
    bf16x8 o;
    o[0] = (short)f2bf(f0.x); o[1] = (short)f2bf(f0.y);
    o[2] = (short)f2bf(f0.z); o[3] = (short)f2bf(f0.w);
    o[4] = (short)f2bf(f1.x); o[5] = (short)f2bf(f1.y);
    o[6] = (short)f2bf(f1.z); o[7] = (short)f2bf(f1.w);
    *(bf16x8*)&out[(size_t)i * 8] = o;
  } else {
    int wid = bid - 6144;
    int z = wid >> 8, rem = wid & 255;
    int by = (rem >> 4) * 64, bx = (rem & 15) * 64;
    const float* in = z == 0 ? w0 : (z == 1 ? w1 : (z == 2 ? w2 : w3));
    u16* out = z == 0 ? o0 : (z == 1 ? o1 : (z == 2 ? o2 : o3));
    int r0 = tid >> 6, c = tid & 63;
    #pragma unroll
    for (int i = 0; i < 64; i += 4) t[r0 + i][c] = in[(size_t)(by + r0 + i) * 1024 + bx + c];
    __syncthreads();
    #pragma unroll
    for (int i = 0; i < 64; i += 4) out[(size_t)(bx + r0 + i) * 1024 + by + c] = f2bf(t[c][r0 + i]);
  }
}

// ---------------- fused QKV GEMM: z in {0,1,2}; C[4096][1024] = A_z @ Wt_z^T, (acc+bias)*scale ----
// q additionally scaled by log2(e) for the exp2 softmax path.
// z==2 (v): the normal C-write is replaced by a fused transpose epilogue that writes
// vt[(b*16+h)][d][s] = acc+bias directly (two 64-col passes through padded LDS T) — k_tr_v removed.
__global__ __launch_bounds__(256) void k_gemm_qkv(const u16* __restrict__ A0, const u16* __restrict__ A1,
                                                  const u16* __restrict__ A2,
                                                  const u16* __restrict__ W0, const u16* __restrict__ W1,
                                                  const u16* __restrict__ W2,
                                                  const float* __restrict__ b0, const float* __restrict__ b1,
                                                  const float* __restrict__ b2,
                                                  u16* __restrict__ C0, u16* __restrict__ C1,
                                                  u16* __restrict__ vt)
{
  int z = blockIdx.z;
  const u16* A  = z == 0 ? A0 : (z == 1 ? A1 : A2);
  const u16* Wt = z == 0 ? W0 : (z == 1 ? W1 : W2);
  const float* bias = z == 0 ? b0 : (z == 1 ? b1 : b2);
  float scale = z == 0 ? (1.44269504f / 64.0f) : 1.0f;   // fold 1/(8*8) and log2e into q

  __shared__ u16 As[128 * 32];       // unpadded: lane-linear for global_load_lds
  __shared__ u16 Bs[128 * 32];
  __shared__ u16 T[64 * 136];        // transpose staging (row stride 136 u16 = 272B, 16B-multiple)
  const int K = 1024, N = 1024;
  int tid = threadIdx.x;
  int lane = tid & 63, wave = tid >> 6;
  int quad = lane >> 4, c16 = lane & 15;
  int wm = wave >> 1, wn = wave & 1;
  int m0 = blockIdx.x * 128, n0 = blockIdx.y * 128;

  f32x4 acc[4][4] = {};

  for (int k0 = 0; k0 < K; k0 += 32) {
    #pragma unroll
    for (int i = 0; i < 2; i++) {
      int slot = tid + i * 256;                 // 128 rows x 4 chunks(16B)
      int r = slot >> 2, cc = (slot & 3) * 8;
      gload_lds16(&A [(size_t)(m0 + r) * K + k0 + cc], &As[slot * 8]);
      gload_lds16(&Wt[(size_t)(n0 + r) * K + k0 + cc], &Bs[slot * 8]);
    }
    __syncthreads();
    bf16x8 af[4], bfr[4];
    #pragma unroll
    for (int mt = 0; mt < 4; mt++) af[mt]  = *(const bf16x8*)&As[(wm * 64 + mt * 16 + c16) * 32 + quad * 8];
    #pragma unroll
    for (int nt = 0; nt < 4; nt++) bfr[nt] = *(const bf16x8*)&Bs[(wn * 64 + nt * 16 + c16) * 32 + quad * 8];
    #pragma unroll
    for (int mt = 0; mt < 4; mt++)
      #pragma unroll
      for (int nt = 0; nt < 4; nt++)
        acc[mt][nt] = __builtin_amdgcn_mfma_f32_16x16x32_bf16(af[mt], bfr[nt], acc[mt][nt], 0, 0, 0);
    __syncthreads();
  }

  if (z == 2) {
    // fused v-transpose epilogue: vt[(b*16+h)*64 + d][s] = acc + bias (scale==1)
    int b_ = m0 >> 11;                 // batch (2048 rows each)
    int s_base = m0 & 2047;
    #pragma unroll
    for (int p = 0; p < 2; p++) {      // pass p handles cols n0+p*64 .. +64 (head (n0>>6)+p)
      if (wn == p) {
        #pragma unroll
        for (int nt = 0; nt < 4; nt++) {
          float bv2 = bias[n0 + p * 64 + nt * 16 + c16];
          #pragma unroll
          for (int mt = 0; mt < 4; mt++) {
            union { u16 u[4]; uint64_t qw; } pk;
            #pragma unroll
            for (int r = 0; r < 4; r++) pk.u[r] = f2bf(acc[mt][nt][r] + bv2);
            *(uint64_t*)&T[(nt * 16 + c16) * 136 + wm * 64 + mt * 16 + quad * 4] = pk.qw;
          }
        }
      }
      __syncthreads();
      {
        int d = tid >> 2, ch = tid & 3;
        int hh = (n0 >> 6) + p;
        u16* vrow = vt + ((size_t)(b_ * 16 + hh) * 64 + d) * S_LEN + s_base + ch * 32;
        #pragma unroll
        for (int j = 0; j < 4; j++)
          *(bf16x8*)&vrow[j * 8] = *(const bf16x8*)&T[d * 136 + ch * 32 + j * 8];
      }
      __syncthreads();
    }
  } else {
    u16* C = z == 0 ? C0 : C1;
    #pragma unroll
    for (int nt = 0; nt < 4; nt++) {
      int gc = n0 + wn * 64 + nt * 16 + c16;
      float bv2 = bias[gc];
      #pragma unroll
      for (int mt = 0; mt < 4; mt++)
        #pragma unroll
        for (int r = 0; r < 4; r++) {
          int gr = m0 + wm * 64 + mt * 16 + quad * 4 + r;
          C[(size_t)gr * N + gc] = f2bf((acc[mt][nt][r] + bv2) * scale);
        }
    }
  }
}

// ---------------- O-proj GEMM: 128x64 tiles (512 blocks, 2/CU), f32 out ----------------
__global__ __launch_bounds__(256) void k_gemm_o(const u16* __restrict__ A, const u16* __restrict__ Wt,
                                                const float* __restrict__ bias, float* __restrict__ C)
{
  __shared__ u16 As[128 * 32];
  __shared__ u16 Bs[64 * 32];
  const int K = 1024, N = 1024;
  int tid = threadIdx.x;
  int lane = tid & 63, wave = tid >> 6;
  int quad = lane >> 4, c16 = lane & 15;
  int wm = wave >> 1, wn = wave & 1;            // wave tile 64x32
  int m0 = blockIdx.x * 128, n0 = blockIdx.y * 64;

  f32x4 acc[4][2] = {};

  for (int k0 = 0; k0 < K; k0 += 32) {
    #pragma unroll
    for (int i = 0; i < 2; i++) {                // A: 128 rows x 4 chunks = 512 chunks
      int slot = tid + i * 256;
      int r = slot >> 2, cc = (slot & 3) * 8;
      gload_lds16(&A[(size_t)(m0 + r) * K + k0 + cc], &As[slot * 8]);
    }
    {                                            // B: 64 rows x 4 chunks = 256 chunks
      int r = tid >> 2, cc = (tid & 3) * 8;
      gload_lds16(&Wt[(size_t)(n0 + r) * K + k0 + cc], &Bs[tid * 8]);
    }
    __syncthreads();
    bf16x8 af[4], bfr[2];
    #pragma unroll
    for (int mt = 0; mt < 4; mt++) af[mt]  = *(const bf16x8*)&As[(wm * 64 + mt * 16 + c16) * 32 + quad * 8];
    #pragma unroll
    for (int nt = 0; nt < 2; nt++) bfr[nt] = *(const bf16x8*)&Bs[(wn * 32 + nt * 16 + c16) * 32 + quad * 8];
    #pragma unroll
    for (int mt = 0; mt < 4; mt++)
      #pragma unroll
      for (int nt = 0; nt < 2; nt++)
        acc[mt][nt] = __builtin_amdgcn_mfma_f32_16x16x32_bf16(af[mt], bfr[nt], acc[mt][nt], 0, 0, 0);
    __syncthreads();
  }

  #pragma unroll
  for (int nt = 0; nt < 2; nt++) {
    int gc = n0 + wn * 32 + nt * 16 + c16;
    float bv2 = bias[gc];
    #pragma unroll
    for (int mt = 0; mt < 4; mt++)
      #pragma unroll
      for (int r = 0; r < 4; r++) {
        int gr = m0 + wm * 64 + mt * 16 + quad * 4 + r;
        C[(size_t)gr * N + gc] = acc[mt][nt][r] + bv2;
      }
  }
}

// ---------------- flash attention: UNCHANGED from round 6 (verified 55.6us) ----------------
__global__ __launch_bounds__(256, 2) void k_attn(const u16* __restrict__ Qm,
                                                 const u16* __restrict__ Km,
                                                 const u16* __restrict__ VTm,
                                                 const float* __restrict__ mask,
                                                 u16* __restrict__ Om)
{
  __shared__ u16 KV[2][9216];        // [buf][K: 64x72 | VT: 64x72] (72 = 9 chunks of 16B)
  __shared__ float Msall[S_LEN];     // mask additive terms (pre-scaled by log2e), staged once
  const int NT = S_LEN / 64;
  int tid = threadIdx.x;
  int lane = tid & 63, wave = tid >> 6;         // wave 0..3
  int quad = lane >> 4, c16 = lane & 15;
  int wq = wave >> 1, wkv = wave & 1;           // q-half, kv-half
  int qb = blockIdx.x, h = blockIdx.y, b = blockIdx.z;
  const size_t SH = (size_t)S_LEN * HDIM;
  const u16* Qbase  = Qm + (size_t)b * SH + (size_t)qb * 128 * HDIM + h * 64;
  const u16* Kbase  = Km + (size_t)b * SH + h * 64;
  const u16* VTbase = VTm + (size_t)(b * NHEAD + h) * 64 * S_LEN;
  const float* Mbase = mask + (size_t)b * S_LEN;

  auto stage = [&](int s0, int bb) {
    #pragma unroll
    for (int i = 0; i < 5; i++) {
      int c = i * 256 + tid;
      if (c < 576) {
        int r = c / 9, cc = c - r * 9;
        int col = (cc == 8) ? 0 : cc * 8;
        gload_lds16(&Kbase[(size_t)(s0 + r) * HDIM + col], &KV[bb][c * 8]);
      } else if (c < 1152) {
        int c2 = c - 576;
        int r = c2 / 9, cc = c2 - r * 9;
        int col = (cc == 8) ? 0 : cc * 8;
        gload_lds16(&VTbase[(size_t)r * S_LEN + s0 + col], &KV[bb][4608 + c2 * 8]);
      }
    }
  };

  stage(0, 0);
  for (int i = tid; i < S_LEN; i += 256) Msall[i] = (1.0f - Mbase[i]) * (-1.8033688e9f);  // (-1e10)/8*log2e

  int qw0 = wq * 64;                            // wave's 64 q-rows
  int kv0 = wkv * 32;                           // wave's 32-kv slice within each tile

  bf16x8 bq[4][2];
  #pragma unroll
  for (int qt = 0; qt < 4; qt++)
    #pragma unroll
    for (int kk = 0; kk < 2; kk++)
      bq[qt][kk] = *(const bf16x8*)&Qbase[(size_t)(qw0 + qt * 16 + c16) * HDIM + kk * 32 + quad * 8];

  f32x4 oacc[4][4] = {};       // D[q=qt*16+quad*4+r][d=dt*16+c16], partial over this wave's kv slices
  float lsq[4] = {};           // per-lane partial denominators for q = qt*16+c16

  __syncthreads();                              // tile 0 + Msall ready

  for (int kt = 0; kt < NT; kt++) {
    int s0 = kt * 64;
    int cb = kt & 1;
    const u16* Kb = &KV[cb][0];
    const u16* Vb = &KV[cb][4608];
    if (kt + 1 < NT) stage(s0 + 64, cb ^ 1);    // async prefetch, drained by end barrier

    f32x4 madd[2];
    #pragma unroll
    for (int kv2 = 0; kv2 < 2; kv2++) madd[kv2] = *(const f32x4*)&Msall[s0 + kv0 + kv2 * 16 + quad * 4];

    bf16x8 ak0[2], ak1[2];
    #pragma unroll
    for (int kv2 = 0; kv2 < 2; kv2++) {
      ak0[kv2] = *(const bf16x8*)&Kb[(kv0 + kv2 * 16 + c16) * 72 + quad * 8];
      ak1[kv2] = *(const bf16x8*)&Kb[(kv0 + kv2 * 16 + c16) * 72 + 32 + quad * 8];
    }
    f32x4 sacc[2][4];
    __builtin_amdgcn_s_setprio(1);
    #pragma unroll
    for (int kv2 = 0; kv2 < 2; kv2++)
      #pragma unroll
      for (int qt = 0; qt < 4; qt++)
        sacc[kv2][qt] = __builtin_amdgcn_mfma_f32_16x16x32_bf16(ak0[kv2], bq[qt][0], madd[kv2], 0, 0, 0);
    #pragma unroll
    for (int kv2 = 0; kv2 < 2; kv2++)
      #pragma unroll
      for (int qt = 0; qt < 4; qt++)
        sacc[kv2][qt] = __builtin_amdgcn_mfma_f32_16x16x32_bf16(ak1[kv2], bq[qt][1], sacc[kv2][qt], 0, 0, 0);
    __builtin_amdgcn_s_setprio(0);

    bf16x4 pa[4][2];
    #pragma unroll
    for (int kv2 = 0; kv2 < 2; kv2++)
      #pragma unroll
      for (int qt = 0; qt < 4; qt++) {
        float p0 = exp2_fast(sacc[kv2][qt][0]);
        float p1 = exp2_fast(sacc[kv2][qt][1]);
        float p2 = exp2_fast(sacc[kv2][qt][2]);
        float p3 = exp2_fast(sacc[kv2][qt][3]);
        lsq[qt] += (p0 + p1) + (p2 + p3);
        union { uint32_t u[2]; bf16x4 v; } cv;
        asm("v_cvt_pk_bf16_f32 %0, %1, %2" : "=v"(cv.u[0]) : "v"(p0), "v"(p1));
        asm("v_cvt_pk_bf16_f32 %0, %1, %2" : "=v"(cv.u[1]) : "v"(p2), "v"(p3));
        pa[qt][kv2] = cv.v;
      }

    __builtin_amdgcn_s_setprio(1);
    #pragma unroll
    for (int kv2 = 0; kv2 < 2; kv2++) {
      bf16x4 vb[4];
      #pragma unroll
      for (int dt = 0; dt < 4; dt++)
        vb[dt] = *(const bf16x4*)&Vb[(dt * 16 + c16) * 72 + kv0 + kv2 * 16 + quad * 4];
      #pragma unroll
      for (int qt = 0; qt < 4; qt++)
        #pragma unroll
        for (int dt = 0; dt < 4; dt++)
          oacc[qt][dt] = __builtin_amdgcn_mfma_f32_16x16x16bf16_1k(pa[qt][kv2], vb[dt], oacc[qt][dt], 0, 0, 0);
    }
    __builtin_amdgcn_s_setprio(0);
    __syncthreads();      // (a) all reads of buf cb done -> reusable; (b) vmcnt(0) drains prefetch
  }

  #pragma unroll
  for (int qt = 0; qt < 4; qt++) {
    float v = lsq[qt];
    v += __shfl_xor(v, 16);
    v += __shfl_xor(v, 32);
    lsq[qt] = v;
  }

  float* Osc = (float*)&KV[0][0];               // 2 x 16KB (per wq) <= 36864B
  float* Lsc = Msall;                           // 2 x 64 floats
  if (wkv == 1) {
    float* Ob = Osc + wq * 4096;
    #pragma unroll
    for (int qt = 0; qt < 4; qt++)
      #pragma unroll
      for (int dt = 0; dt < 4; dt++)
        #pragma unroll
        for (int r = 0; r < 4; r++)
          Ob[(qt * 16 + quad * 4 + r) * 64 + dt * 16 + c16] = oacc[qt][dt][r];
    if (lane < 16)
      #pragma unroll
      for (int qt = 0; qt < 4; qt++) Lsc[wq * 64 + qt * 16 + lane] = lsq[qt];
  }
  __syncthreads();
  if (wkv == 0) {
    float* Ob = Osc + wq * 4096;
    u16* Obase = Om + (size_t)b * SH + (size_t)qb * 128 * HDIM + h * 64;
    #pragma unroll
    for (int qt = 0; qt < 4; qt++)
      #pragma unroll
      for (int r = 0; r < 4; r++) {
        float l = __shfl(lsq[qt], quad * 4 + r) + Lsc[wq * 64 + qt * 16 + quad * 4 + r];
        float rinv = 1.0f / l;
        int lr = qw0 + qt * 16 + quad * 4 + r;
        #pragma unroll
        for (int dt = 0; dt < 4; dt++) {
          float o = oacc[qt][dt][r] + Ob[(qt * 16 + quad * 4 + r) * 64 + dt * 16 + c16];
          Obase[(size_t)lr * HDIM + dt * 16 + c16] = f2bf(o * rinv);
        }
      }
  }
}

extern "C" void kernel_launch(void* const* d_in, const int* in_sizes, int n_in,
                              void* d_out, int out_size, void* d_ws, size_t ws_size,
                              hipStream_t stream)
{
  (void)in_sizes; (void)n_in; (void)out_size; (void)ws_size;
  const float* q_in = (const float*)d_in[0];
  const float* k_in = (const float*)d_in[1];
  const float* v_in = (const float*)d_in[2];
  const float* mask = (const float*)d_in[3];
  const float* wq   = (const float*)d_in[4];
  const float* bq   = (const float*)d_in[5];
  const float* wk   = (const float*)d_in[6];
  const float* bk   = (const float*)d_in[7];
  const float* wv   = (const float*)d_in[8];
  const float* bv   = (const float*)d_in[9];
  const float* wo   = (const float*)d_in[10];
  const float* bo   = (const float*)d_in[11];

  u16* ws  = (u16*)d_ws;                 // bf16 elems: 4x1M wt + 3x4M in + acts
  u16* wqt = ws;
  u16* wkt = wqt + (1u << 20);
  u16* wvt = wkt + (1u << 20);
  u16* wot = wvt + (1u << 20);
  u16* qi_ = wot + (1u << 20);
  u16* ki_ = qi_ + (4u << 20);
  u16* vi_ = ki_ + (4u << 20);
  u16* qb_ = vi_ + (4u << 20);
  u16* kb_ = qb_ + (4u << 20);
  u16* vb_ = kb_ + (4u << 20);   // unused (v GEMM writes transposed directly)
  u16* vtb = vb_ + (4u << 20);
  u16* ob_ = vtb + (4u << 20);

  dim3 blk(256);
  k_pre<<<dim3(7168), blk, 0, stream>>>(q_in, k_in, v_in, qi_, ki_, vi_,
                                        wq, wk, wv, wo, wqt, wkt, wvt, wot);
  k_gemm_qkv<<<dim3(32, 8, 3), blk, 0, stream>>>(qi_, ki_, vi_, wqt, wkt, wvt, bq, bk, bv,
                                                 qb_, kb_, vtb);
  k_attn<<<dim3(16, 16, 2), blk, 0, stream>>>(qb_, kb_, vtb, mask, ob_);
  k_gemm_o<<<dim3(32, 16), blk, 0, stream>>>(ob_, wot, bo, (float*)d_out);
}

// Round 8
// 230.843 us; speedup vs baseline: 1.0216x; 1.0216x over previous
//
#include <hip/hip_runtime.h>
#include <cstdint>

typedef unsigned short u16;
typedef __attribute__((ext_vector_type(8))) short bf16x8;   // 8 bf16 = 4 VGPRs
typedef __attribute__((ext_vector_type(4))) short bf16x4;   // 4 bf16 = 2 VGPRs
typedef __attribute__((ext_vector_type(4))) float f32x4;

#define S_LEN 2048
#define HDIM  1024
#define NHEAD 16

__device__ __forceinline__ float bf2f(u16 u){ return __uint_as_float(((uint32_t)u) << 16); }
__device__ __forceinline__ u16 f2bf(float f){
  uint32_t x = __float_as_uint(f);
  return (u16)((x + 0x7fffu + ((x >> 16) & 1u)) >> 16);   // RNE
}

// 2^x via the native v_exp_f32 (gfx950: v_exp_f32 computes 2^S0)
__device__ __forceinline__ float exp2_fast(float x){
  float r; asm("v_exp_f32 %0, %1" : "=v"(r) : "v"(x)); return r;
}

// async global->LDS 16B (m97 idiom). LDS dest is wave-uniform base + lane*16.
__device__ __forceinline__ void gload_lds16(const void* g, void* l){
  __builtin_amdgcn_global_load_lds((const __attribute__((address_space(1))) void*)g,
                                   (__attribute__((address_space(3))) void*)l, 16, 0, 0);
}

// ---------------- f32 -> bf16 elementwise, batched over {q,k,v} via blockIdx.y ----------------
__global__ __launch_bounds__(256) void k_cvt3(const float* __restrict__ q, const float* __restrict__ k,
                                              const float* __restrict__ v, u16* __restrict__ oq,
                                              u16* __restrict__ ok, u16* __restrict__ ov){
  int z = blockIdx.y;
  const float* in = z == 0 ? q : (z == 1 ? k : v);
  u16* out = z == 0 ? oq : (z == 1 ? ok : ov);
  int i = blockIdx.x * 256 + threadIdx.x;     // 8 elems/thread, 4M elems total
  float4 f0 = *(const float4*)&in[(size_t)i * 8];
  float4 f1 = *(const float4*)&in[(size_t)i * 8 + 4];
  bf16x8 o;
  o[0] = (short)f2bf(f0.x); o[1] = (short)f2bf(f0.y);
  o[2] = (short)f2bf(f0.z); o[3] = (short)f2bf(f0.w);
  o[4] = (short)f2bf(f1.x); o[5] = (short)f2bf(f1.y);
  o[6] = (short)f2bf(f1.z); o[7] = (short)f2bf(f1.w);
  *(bf16x8*)&out[(size_t)i * 8] = o;
}

// ---------------- weight transpose + cvt, batched over 4 weights: wt[n][k] = w[k][n] ----------------
__global__ __launch_bounds__(256) void k_tr_w4(const float* __restrict__ w0, const float* __restrict__ w1,
                                               const float* __restrict__ w2, const float* __restrict__ w3,
                                               u16* __restrict__ o0, u16* __restrict__ o1,
                                               u16* __restrict__ o2, u16* __restrict__ o3){
  int z = blockIdx.z;
  const float* in = z == 0 ? w0 : (z == 1 ? w1 : (z == 2 ? w2 : w3));
  u16* out = z == 0 ? o0 : (z == 1 ? o1 : (z == 2 ? o2 : o3));
  __shared__ float t[64][65];
  int r0 = threadIdx.x >> 6;          // 0..3
  int c  = threadIdx.x & 63;
  int bx = blockIdx.x * 64, by = blockIdx.y * 64;
  #pragma unroll
  for (int i = 0; i < 64; i += 4) t[r0 + i][c] = in[(size_t)(by + r0 + i) * 1024 + bx + c];
  __syncthreads();
  #pragma unroll
  for (int i = 0; i < 64; i += 4) out[(size_t)(bx + r0 + i) * 1024 + by + c] = f2bf(t[c][r0 + i]);
}

// ---------------- v transpose (bf16->bf16): vt[b*16+h][d][s] = v[b][s][h*64+d] ----------------
__global__ __launch_bounds__(256) void k_tr_v(const u16* __restrict__ v, u16* __restrict__ vt){
  __shared__ u16 t[64][65];
  int r0 = threadIdx.x >> 6, c = threadIdx.x & 63;
  int s0 = blockIdx.x * 64;
  int bh = blockIdx.y;                // b*16+h
  int b = bh >> 4, h = bh & 15;
  const u16* src = v + (size_t)b * S_LEN * HDIM + h * 64;
  #pragma unroll
  for (int i = 0; i < 64; i += 4) t[r0 + i][c] = src[(size_t)(s0 + r0 + i) * HDIM + c];
  __syncthreads();
  u16* dst = vt + (size_t)bh * 64 * S_LEN + s0;
  #pragma unroll
  for (int i = 0; i < 64; i += 4) dst[(size_t)(r0 + i) * S_LEN + c] = t[c][r0 + i];
}

// ---------------- fused QKV GEMM: z in {0,1,2}; C[4096][1024] = A_z @ Wt_z^T, (acc+bias)*scale ----
// q additionally scaled by log2(e) for the exp2 softmax path.
// This round: double-buffered LDS, prefetch(k0+32) issued BEFORE compute(k0), ONE barrier per
// K-step (the verified attn loop structure) — halves barriers and overlaps staging with MFMA.
__global__ __launch_bounds__(256) void k_gemm_qkv(const u16* __restrict__ A0, const u16* __restrict__ A1,
                                                  const u16* __restrict__ A2,
                                                  const u16* __restrict__ W0, const u16* __restrict__ W1,
                                                  const u16* __restrict__ W2,
                                                  const float* __restrict__ b0, const float* __restrict__ b1,
                                                  const float* __restrict__ b2,
                                                  u16* __restrict__ C0, u16* __restrict__ C1,
                                                  u16* __restrict__ C2)
{
  int z = blockIdx.z;
  const u16* A  = z == 0 ? A0 : (z == 1 ? A1 : A2);
  const u16* Wt = z == 0 ? W0 : (z == 1 ? W1 : W2);
  const float* bias = z == 0 ? b0 : (z == 1 ? b1 : b2);
  u16* C = z == 0 ? C0 : (z == 1 ? C1 : C2);
  float scale = z == 0 ? (1.44269504f / 64.0f) : 1.0f;   // fold 1/(8*8) and log2e into q

  __shared__ u16 As[2][128 * 32];    // unpadded: lane-linear for global_load_lds
  __shared__ u16 Bs[2][128 * 32];
  const int K = 1024, N = 1024;
  int tid = threadIdx.x;
  int lane = tid & 63, wave = tid >> 6;
  int quad = lane >> 4, c16 = lane & 15;
  int wm = wave >> 1, wn = wave & 1;
  int m0 = blockIdx.x * 128, n0 = blockIdx.y * 128;

  auto stageAB = [&](int k0, int bb) {
    #pragma unroll
    for (int i = 0; i < 2; i++) {
      int slot = tid + i * 256;                 // 128 rows x 4 chunks(16B)
      int r = slot >> 2, cc = (slot & 3) * 8;
      gload_lds16(&A [(size_t)(m0 + r) * K + k0 + cc], &As[bb][slot * 8]);
      gload_lds16(&Wt[(size_t)(n0 + r) * K + k0 + cc], &Bs[bb][slot * 8]);
    }
  };

  f32x4 acc[4][4] = {};

  stageAB(0, 0);
  __syncthreads();                              // tile 0 ready

  for (int k0 = 0; k0 < K; k0 += 32) {
    int cb = (k0 >> 5) & 1;
    if (k0 + 32 < K) stageAB(k0 + 32, cb ^ 1);  // async prefetch, drained by end barrier
    bf16x8 af[4], bfr[4];
    #pragma unroll
    for (int mt = 0; mt < 4; mt++) af[mt]  = *(const bf16x8*)&As[cb][(wm * 64 + mt * 16 + c16) * 32 + quad * 8];
    #pragma unroll
    for (int nt = 0; nt < 4; nt++) bfr[nt] = *(const bf16x8*)&Bs[cb][(wn * 64 + nt * 16 + c16) * 32 + quad * 8];
    #pragma unroll
    for (int mt = 0; mt < 4; mt++)
      #pragma unroll
      for (int nt = 0; nt < 4; nt++)
        acc[mt][nt] = __builtin_amdgcn_mfma_f32_16x16x32_bf16(af[mt], bfr[nt], acc[mt][nt], 0, 0, 0);
    __syncthreads();      // (a) reads of buf cb done -> reusable; (b) vmcnt(0) drains prefetch
  }

  #pragma unroll
  for (int nt = 0; nt < 4; nt++) {
    int gc = n0 + wn * 64 + nt * 16 + c16;
    float bv = bias[gc];
    #pragma unroll
    for (int mt = 0; mt < 4; mt++)
      #pragma unroll
      for (int r = 0; r < 4; r++) {
        int gr = m0 + wm * 64 + mt * 16 + quad * 4 + r;
        C[(size_t)gr * N + gc] = f2bf((acc[mt][nt][r] + bv) * scale);
      }
  }
}

// ---------------- O-proj GEMM: 128x64 tiles (512 blocks, 2/CU), f32 out ----------------
// Same double-buffered single-barrier prefetch loop as k_gemm_qkv.
__global__ __launch_bounds__(256) void k_gemm_o(const u16* __restrict__ A, const u16* __restrict__ Wt,
                                                const float* __restrict__ bias, float* __restrict__ C)
{
  __shared__ u16 As[2][128 * 32];
  __shared__ u16 Bs[2][64 * 32];
  const int K = 1024, N = 1024;
  int tid = threadIdx.x;
  int lane = tid & 63, wave = tid >> 6;
  int quad = lane >> 4, c16 = lane & 15;
  int wm = wave >> 1, wn = wave & 1;            // wave tile 64x32
  int m0 = blockIdx.x * 128, n0 = blockIdx.y * 64;

  auto stageAB = [&](int k0, int bb) {
    #pragma unroll
    for (int i = 0; i < 2; i++) {                // A: 128 rows x 4 chunks = 512 chunks
      int slot = tid + i * 256;
      int r = slot >> 2, cc = (slot & 3) * 8;
      gload_lds16(&A[(size_t)(m0 + r) * K + k0 + cc], &As[bb][slot * 8]);
    }
    {                                            // B: 64 rows x 4 chunks = 256 chunks
      int r = tid >> 2, cc = (tid & 3) * 8;
      gload_lds16(&Wt[(size_t)(n0 + r) * K + k0 + cc], &Bs[bb][tid * 8]);
    }
  };

  f32x4 acc[4][2] = {};

  stageAB(0, 0);
  __syncthreads();                              // tile 0 ready

  for (int k0 = 0; k0 < K; k0 += 32) {
    int cb = (k0 >> 5) & 1;
    if (k0 + 32 < K) stageAB(k0 + 32, cb ^ 1);  // async prefetch, drained by end barrier
    bf16x8 af[4], bfr[2];
    #pragma unroll
    for (int mt = 0; mt < 4; mt++) af[mt]  = *(const bf16x8*)&As[cb][(wm * 64 + mt * 16 + c16) * 32 + quad * 8];
    #pragma unroll
    for (int nt = 0; nt < 2; nt++) bfr[nt] = *(const bf16x8*)&Bs[cb][(wn * 32 + nt * 16 + c16) * 32 + quad * 8];
    #pragma unroll
    for (int mt = 0; mt < 4; mt++)
      #pragma unroll
      for (int nt = 0; nt < 2; nt++)
        acc[mt][nt] = __builtin_amdgcn_mfma_f32_16x16x32_bf16(af[mt], bfr[nt], acc[mt][nt], 0, 0, 0);
    __syncthreads();
  }

  #pragma unroll
  for (int nt = 0; nt < 2; nt++) {
    int gc = n0 + wn * 32 + nt * 16 + c16;
    float bv = bias[gc];
    #pragma unroll
    for (int mt = 0; mt < 4; mt++)
      #pragma unroll
      for (int r = 0; r < 4; r++) {
        int gr = m0 + wm * 64 + mt * 16 + quad * 4 + r;
        C[(size_t)gr * N + gc] = acc[mt][nt][r] + bv;
      }
  }
}

// ---------------- flash attention: UNCHANGED from round 6 (verified 55.6us) ----------------
__global__ __launch_bounds__(256, 2) void k_attn(const u16* __restrict__ Qm,
                                                 const u16* __restrict__ Km,
                                                 const u16* __restrict__ VTm,
                                                 const float* __restrict__ mask,
                                                 u16* __restrict__ Om)
{
  __shared__ u16 KV[2][9216];        // [buf][K: 64x72 | VT: 64x72] (72 = 9 chunks of 16B)
  __shared__ float Msall[S_LEN];     // mask additive terms (pre-scaled by log2e), staged once
  const int NT = S_LEN / 64;
  int tid = threadIdx.x;
  int lane = tid & 63, wave = tid >> 6;         // wave 0..3
  int quad = lane >> 4, c16 = lane & 15;
  int wq = wave >> 1, wkv = wave & 1;           // q-half, kv-half
  int qb = blockIdx.x, h = blockIdx.y, b = blockIdx.z;
  const size_t SH = (size_t)S_LEN * HDIM;
  const u16* Qbase  = Qm + (size_t)b * SH + (size_t)qb * 128 * HDIM + h * 64;
  const u16* Kbase  = Km + (size_t)b * SH + h * 64;
  const u16* VTbase = VTm + (size_t)(b * NHEAD + h) * 64 * S_LEN;
  const float* Mbase = mask + (size_t)b * S_LEN;

  auto stage = [&](int s0, int bb) {
    #pragma unroll
    for (int i = 0; i < 5; i++) {
      int c = i * 256 + tid;
      if (c < 576) {
        int r = c / 9, cc = c - r * 9;
        int col = (cc == 8) ? 0 : cc * 8;
        gload_lds16(&Kbase[(size_t)(s0 + r) * HDIM + col], &KV[bb][c * 8]);
      } else if (c < 1152) {
        int c2 = c - 576;
        int r = c2 / 9, cc = c2 - r * 9;
        int col = (cc == 8) ? 0 : cc * 8;
        gload_lds16(&VTbase[(size_t)r * S_LEN + s0 + col], &KV[bb][4608 + c2 * 8]);
      }
    }
  };

  stage(0, 0);
  for (int i = tid; i < S_LEN; i += 256) Msall[i] = (1.0f - Mbase[i]) * (-1.8033688e9f);  // (-1e10)/8*log2e

  int qw0 = wq * 64;                            // wave's 64 q-rows
  int kv0 = wkv * 32;                           // wave's 32-kv slice within each tile

  bf16x8 bq[4][2];
  #pragma unroll
  for (int qt = 0; qt < 4; qt++)
    #pragma unroll
    for (int kk = 0; kk < 2; kk++)
      bq[qt][kk] = *(const bf16x8*)&Qbase[(size_t)(qw0 + qt * 16 + c16) * HDIM + kk * 32 + quad * 8];

  f32x4 oacc[4][4] = {};       // D[q=qt*16+quad*4+r][d=dt*16+c16], partial over this wave's kv slices
  float lsq[4] = {};           // per-lane partial denominators for q = qt*16+c16

  __syncthreads();                              // tile 0 + Msall ready

  for (int kt = 0; kt < NT; kt++) {
    int s0 = kt * 64;
    int cb = kt & 1;
    const u16* Kb = &KV[cb][0];
    const u16* Vb = &KV[cb][4608];
    if (kt + 1 < NT) stage(s0 + 64, cb ^ 1);    // async prefetch, drained by end barrier

    f32x4 madd[2];
    #pragma unroll
    for (int kv2 = 0; kv2 < 2; kv2++) madd[kv2] = *(const f32x4*)&Msall[s0 + kv0 + kv2 * 16 + quad * 4];

    bf16x8 ak0[2], ak1[2];
    #pragma unroll
    for (int kv2 = 0; kv2 < 2; kv2++) {
      ak0[kv2] = *(const bf16x8*)&Kb[(kv0 + kv2 * 16 + c16) * 72 + quad * 8];
      ak1[kv2] = *(const bf16x8*)&Kb[(kv0 + kv2 * 16 + c16) * 72 + 32 + quad * 8];
    }
    f32x4 sacc[2][4];
    __builtin_amdgcn_s_setprio(1);
    #pragma unroll
    for (int kv2 = 0; kv2 < 2; kv2++)
      #pragma unroll
      for (int qt = 0; qt < 4; qt++)
        sacc[kv2][qt] = __builtin_amdgcn_mfma_f32_16x16x32_bf16(ak0[kv2], bq[qt][0], madd[kv2], 0, 0, 0);
    #pragma unroll
    for (int kv2 = 0; kv2 < 2; kv2++)
      #pragma unroll
      for (int qt = 0; qt < 4; qt++)
        sacc[kv2][qt] = __builtin_amdgcn_mfma_f32_16x16x32_bf16(ak1[kv2], bq[qt][1], sacc[kv2][qt], 0, 0, 0);
    __builtin_amdgcn_s_setprio(0);

    bf16x4 pa[4][2];
    #pragma unroll
    for (int kv2 = 0; kv2 < 2; kv2++)
      #pragma unroll
      for (int qt = 0; qt < 4; qt++) {
        float p0 = exp2_fast(sacc[kv2][qt][0]);
        float p1 = exp2_fast(sacc[kv2][qt][1]);
        float p2 = exp2_fast(sacc[kv2][qt][2]);
        float p3 = exp2_fast(sacc[kv2][qt][3]);
        lsq[qt] += (p0 + p1) + (p2 + p3);
        union { uint32_t u[2]; bf16x4 v; } cv;
        asm("v_cvt_pk_bf16_f32 %0, %1, %2" : "=v"(cv.u[0]) : "v"(p0), "v"(p1));
        asm("v_cvt_pk_bf16_f32 %0, %1, %2" : "=v"(cv.u[1]) : "v"(p2), "v"(p3));
        pa[qt][kv2] = cv.v;
      }

    __builtin_amdgcn_s_setprio(1);
    #pragma unroll
    for (int kv2 = 0; kv2 < 2; kv2++) {
      bf16x4 vb[4];
      #pragma unroll
      for (int dt = 0; dt < 4; dt++)
        vb[dt] = *(const bf16x4*)&Vb[(dt * 16 + c16) * 72 + kv0 + kv2 * 16 + quad * 4];
      #pragma unroll
      for (int qt = 0; qt < 4; qt++)
        #pragma unroll
        for (int dt = 0; dt < 4; dt++)
          oacc[qt][dt] = __builtin_amdgcn_mfma_f32_16x16x16bf16_1k(pa[qt][kv2], vb[dt], oacc[qt][dt], 0, 0, 0);
    }
    __builtin_amdgcn_s_setprio(0);
    __syncthreads();      // (a) all reads of buf cb done -> reusable; (b) vmcnt(0) drains prefetch
  }

  #pragma unroll
  for (int qt = 0; qt < 4; qt++) {
    float v = lsq[qt];
    v += __shfl_xor(v, 16);
    v += __shfl_xor(v, 32);
    lsq[qt] = v;
  }

  float* Osc = (float*)&KV[0][0];               // 2 x 16KB (per wq) <= 36864B
  float* Lsc = Msall;                           // 2 x 64 floats
  if (wkv == 1) {
    float* Ob = Osc + wq * 4096;
    #pragma unroll
    for (int qt = 0; qt < 4; qt++)
      #pragma unroll
      for (int dt = 0; dt < 4; dt++)
        #pragma unroll
        for (int r = 0; r < 4; r++)
          Ob[(qt * 16 + quad * 4 + r) * 64 + dt * 16 + c16] = oacc[qt][dt][r];
    if (lane < 16)
      #pragma unroll
      for (int qt = 0; qt < 4; qt++) Lsc[wq * 64 + qt * 16 + lane] = lsq[qt];
  }
  __syncthreads();
  if (wkv == 0) {
    float* Ob = Osc + wq * 4096;
    u16* Obase = Om + (size_t)b * SH + (size_t)qb * 128 * HDIM + h * 64;
    #pragma unroll
    for (int qt = 0; qt < 4; qt++)
      #pragma unroll
      for (int r = 0; r < 4; r++) {
        float l = __shfl(lsq[qt], quad * 4 + r) + Lsc[wq * 64 + qt * 16 + quad * 4 + r];
        float rinv = 1.0f / l;
        int lr = qw0 + qt * 16 + quad * 4 + r;
        #pragma unroll
        for (int dt = 0; dt < 4; dt++) {
          float o = oacc[qt][dt][r] + Ob[(qt * 16 + quad * 4 + r) * 64 + dt * 16 + c16];
          Obase[(size_t)lr * HDIM + dt * 16 + c16] = f2bf(o * rinv);
        }
      }
  }
}

extern "C" void kernel_launch(void* const* d_in, const int* in_sizes, int n_in,
                              void* d_out, int out_size, void* d_ws, size_t ws_size,
                              hipStream_t stream)
{
  (void)in_sizes; (void)n_in; (void)out_size; (void)ws_size;
  const float* q_in = (const float*)d_in[0];
  const float* k_in = (const float*)d_in[1];
  const float* v_in = (const float*)d_in[2];
  const float* mask = (const float*)d_in[3];
  const float* wq   = (const float*)d_in[4];
  const float* bq   = (const float*)d_in[5];
  const float* wk   = (const float*)d_in[6];
  const float* bk   = (const float*)d_in[7];
  const float* wv   = (const float*)d_in[8];
  const float* bv   = (const float*)d_in[9];
  const float* wo   = (const float*)d_in[10];
  const float* bo   = (const float*)d_in[11];

  u16* ws  = (u16*)d_ws;                 // bf16 elems: 4x1M wt + 3x4M in + 5x4M acts = 72 MB
  u16* wqt = ws;
  u16* wkt = wqt + (1u << 20);
  u16* wvt = wkt + (1u << 20);
  u16* wot = wvt + (1u << 20);
  u16* qi_ = wot + (1u << 20);
  u16* ki_ = qi_ + (4u << 20);
  u16* vi_ = ki_ + (4u << 20);
  u16* qb_ = vi_ + (4u << 20);
  u16* kb_ = qb_ + (4u << 20);
  u16* vb_ = kb_ + (4u << 20);
  u16* vtb = vb_ + (4u << 20);
  u16* ob_ = vtb + (4u << 20);

  dim3 blk(256);
  k_cvt3<<<dim3(2048, 3), blk, 0, stream>>>(q_in, k_in, v_in, qi_, ki_, vi_);
  k_tr_w4<<<dim3(16, 16, 4), blk, 0, stream>>>(wq, wk, wv, wo, wqt, wkt, wvt, wot);
  k_gemm_qkv<<<dim3(32, 8, 3), blk, 0, stream>>>(qi_, ki_, vi_, wqt, wkt, wvt, bq, bk, bv, qb_, kb_, vb_);
  k_tr_v<<<dim3(32, 32), blk, 0, stream>>>(vb_, vtb);
  k_attn<<<dim3(16, 16, 2), blk, 0, stream>>>(qb_, kb_, vtb, mask, ob_);
  k_gemm_o<<<dim3(32, 16), blk, 0, stream>>>(ob_, wot, bo, (float*)d_out);
}

// Round 9
// 227.228 us; speedup vs baseline: 1.0379x; 1.0159x over previous
//
#include <hip/hip_runtime.h>
#include <cstdint>

typedef unsigned short u16;
typedef __attribute__((ext_vector_type(8))) short bf16x8;   // 8 bf16 = 4 VGPRs
typedef __attribute__((ext_vector_type(4))) short bf16x4;   // 4 bf16 = 2 VGPRs
typedef __attribute__((ext_vector_type(4))) float f32x4;

#define S_LEN 2048
#define HDIM  1024
#define NHEAD 16

__device__ __forceinline__ float bf2f(u16 u){ return __uint_as_float(((uint32_t)u) << 16); }
__device__ __forceinline__ u16 f2bf(float f){
  uint32_t x = __float_as_uint(f);
  return (u16)((x + 0x7fffu + ((x >> 16) & 1u)) >> 16);   // RNE
}

// 2^x via the native v_exp_f32 (gfx950: v_exp_f32 computes 2^S0)
__device__ __forceinline__ float exp2_fast(float x){
  float r; asm("v_exp_f32 %0, %1" : "=v"(r) : "v"(x)); return r;
}

// async global->LDS 16B (m97 idiom). LDS dest is wave-uniform base + lane*16.
__device__ __forceinline__ void gload_lds16(const void* g, void* l){
  __builtin_amdgcn_global_load_lds((const __attribute__((address_space(1))) void*)g,
                                   (__attribute__((address_space(3))) void*)l, 16, 0, 0);
}

// T1 XCD swizzle (m157): dispatched flat id d (hw round-robins d%8 over XCDs) -> logical id
// such that each XCD owns a contiguous logical chunk. Bijective when n%8==0.
__device__ __forceinline__ int xcd_swz(int d, int n){
  int cpx = n >> 3;
  return (d & 7) * cpx + (d >> 3);
}

// ---------------- f32 -> bf16 elementwise, batched over {q,k,v} via blockIdx.y ----------------
__global__ __launch_bounds__(256) void k_cvt3(const float* __restrict__ q, const float* __restrict__ k,
                                              const float* __restrict__ v, u16* __restrict__ oq,
                                              u16* __restrict__ ok, u16* __restrict__ ov){
  int z = blockIdx.y;
  const float* in = z == 0 ? q : (z == 1 ? k : v);
  u16* out = z == 0 ? oq : (z == 1 ? ok : ov);
  int i = blockIdx.x * 256 + threadIdx.x;     // 8 elems/thread, 4M elems total
  float4 f0 = *(const float4*)&in[(size_t)i * 8];
  float4 f1 = *(const float4*)&in[(size_t)i * 8 + 4];
  bf16x8 o;
  o[0] = (short)f2bf(f0.x); o[1] = (short)f2bf(f0.y);
  o[2] = (short)f2bf(f0.z); o[3] = (short)f2bf(f0.w);
  o[4] = (short)f2bf(f1.x); o[5] = (short)f2bf(f1.y);
  o[6] = (short)f2bf(f1.z); o[7] = (short)f2bf(f1.w);
  *(bf16x8*)&out[(size_t)i * 8] = o;
}

// ---------------- weight transpose + cvt, batched over 4 weights: wt[n][k] = w[k][n] ----------------
__global__ __launch_bounds__(256) void k_tr_w4(const float* __restrict__ w0, const float* __restrict__ w1,
                                               const float* __restrict__ w2, const float* __restrict__ w3,
                                               u16* __restrict__ o0, u16* __restrict__ o1,
                                               u16* __restrict__ o2, u16* __restrict__ o3){
  int z = blockIdx.z;
  const float* in = z == 0 ? w0 : (z == 1 ? w1 : (z == 2 ? w2 : w3));
  u16* out = z == 0 ? o0 : (z == 1 ? o1 : (z == 2 ? o2 : o3));
  __shared__ float t[64][65];
  int r0 = threadIdx.x >> 6;          // 0..3
  int c  = threadIdx.x & 63;
  int bx = blockIdx.x * 64, by = blockIdx.y * 64;
  #pragma unroll
  for (int i = 0; i < 64; i += 4) t[r0 + i][c] = in[(size_t)(by + r0 + i) * 1024 + bx + c];
  __syncthreads();
  #pragma unroll
  for (int i = 0; i < 64; i += 4) out[(size_t)(bx + r0 + i) * 1024 + by + c] = f2bf(t[c][r0 + i]);
}

// ---------------- v transpose (bf16->bf16): vt[b*16+h][d][s] = v[b][s][h*64+d] ----------------
__global__ __launch_bounds__(256) void k_tr_v(const u16* __restrict__ v, u16* __restrict__ vt){
  __shared__ u16 t[64][65];
  int r0 = threadIdx.x >> 6, c = threadIdx.x & 63;
  int s0 = blockIdx.x * 64;
  int bh = blockIdx.y;                // b*16+h
  int b = bh >> 4, h = bh & 15;
  const u16* src = v + (size_t)b * S_LEN * HDIM + h * 64;
  #pragma unroll
  for (int i = 0; i < 64; i += 4) t[r0 + i][c] = src[(size_t)(s0 + r0 + i) * HDIM + c];
  __syncthreads();
  u16* dst = vt + (size_t)bh * 64 * S_LEN + s0;
  #pragma unroll
  for (int i = 0; i < 64; i += 4) dst[(size_t)(r0 + i) * S_LEN + c] = t[c][r0 + i];
}

// ---------------- fused QKV GEMM: z in {0,1,2}; C[4096][1024] = A_z @ Wt_z^T, (acc+bias)*scale ----
// q additionally scaled by log2(e) for the exp2 softmax path.
// Double-buffered LDS, prefetch(k0+32) before compute(k0), one barrier per K-step (r8, kept).
// This round: T1 XCD swizzle — logical id m-major within z so each XCD's chunk of 96 blocks
// shares 12 A-row-panels (3MB) + full W (2MB) in its private L2.
__global__ __launch_bounds__(256) void k_gemm_qkv(const u16* __restrict__ A0, const u16* __restrict__ A1,
                                                  const u16* __restrict__ A2,
                                                  const u16* __restrict__ W0, const u16* __restrict__ W1,
                                                  const u16* __restrict__ W2,
                                                  const float* __restrict__ b0, const float* __restrict__ b1,
                                                  const float* __restrict__ b2,
                                                  u16* __restrict__ C0, u16* __restrict__ C1,
                                                  u16* __restrict__ C2)
{
  int d = blockIdx.x + 32 * (blockIdx.y + 8 * blockIdx.z);   // dispatched flat (x fastest)
  int L = xcd_swz(d, 768);
  int yb = L & 7, xb = (L >> 3) & 31, z = L >> 8;            // n-block, m-block, gemm id

  const u16* A  = z == 0 ? A0 : (z == 1 ? A1 : A2);
  const u16* Wt = z == 0 ? W0 : (z == 1 ? W1 : W2);
  const float* bias = z == 0 ? b0 : (z == 1 ? b1 : b2);
  u16* C = z == 0 ? C0 : (z == 1 ? C1 : C2);
  float scale = z == 0 ? (1.44269504f / 64.0f) : 1.0f;   // fold 1/(8*8) and log2e into q

  __shared__ u16 As[2][128 * 32];    // unpadded: lane-linear for global_load_lds
  __shared__ u16 Bs[2][128 * 32];
  const int K = 1024, N = 1024;
  int tid = threadIdx.x;
  int lane = tid & 63, wave = tid >> 6;
  int quad = lane >> 4, c16 = lane & 15;
  int wm = wave >> 1, wn = wave & 1;
  int m0 = xb * 128, n0 = yb * 128;

  auto stageAB = [&](int k0, int bb) {
    #pragma unroll
    for (int i = 0; i < 2; i++) {
      int slot = tid + i * 256;                 // 128 rows x 4 chunks(16B)
      int r = slot >> 2, cc = (slot & 3) * 8;
      gload_lds16(&A [(size_t)(m0 + r) * K + k0 + cc], &As[bb][slot * 8]);
      gload_lds16(&Wt[(size_t)(n0 + r) * K + k0 + cc], &Bs[bb][slot * 8]);
    }
  };

  f32x4 acc[4][4] = {};

  stageAB(0, 0);
  __syncthreads();                              // tile 0 ready

  for (int k0 = 0; k0 < K; k0 += 32) {
    int cb = (k0 >> 5) & 1;
    if (k0 + 32 < K) stageAB(k0 + 32, cb ^ 1);  // async prefetch, drained by end barrier
    bf16x8 af[4], bfr[4];
    #pragma unroll
    for (int mt = 0; mt < 4; mt++) af[mt]  = *(const bf16x8*)&As[cb][(wm * 64 + mt * 16 + c16) * 32 + quad * 8];
    #pragma unroll
    for (int nt = 0; nt < 4; nt++) bfr[nt] = *(const bf16x8*)&Bs[cb][(wn * 64 + nt * 16 + c16) * 32 + quad * 8];
    #pragma unroll
    for (int mt = 0; mt < 4; mt++)
      #pragma unroll
      for (int nt = 0; nt < 4; nt++)
        acc[mt][nt] = __builtin_amdgcn_mfma_f32_16x16x32_bf16(af[mt], bfr[nt], acc[mt][nt], 0, 0, 0);
    __syncthreads();      // (a) reads of buf cb done -> reusable; (b) vmcnt(0) drains prefetch
  }

  #pragma unroll
  for (int nt = 0; nt < 4; nt++) {
    int gc = n0 + wn * 64 + nt * 16 + c16;
    float bv = bias[gc];
    #pragma unroll
    for (int mt = 0; mt < 4; mt++)
      #pragma unroll
      for (int r = 0; r < 4; r++) {
        int gr = m0 + wm * 64 + mt * 16 + quad * 4 + r;
        C[(size_t)gr * N + gc] = f2bf((acc[mt][nt][r] + bv) * scale);
      }
  }
}

// ---------------- O-proj GEMM: 128x64 tiles (512 blocks), f32 out; dbuf + T1 swizzle ----------------
__global__ __launch_bounds__(256) void k_gemm_o(const u16* __restrict__ A, const u16* __restrict__ Wt,
                                                const float* __restrict__ bias, float* __restrict__ C)
{
  int d = blockIdx.x + 32 * blockIdx.y;
  int L = xcd_swz(d, 512);
  int yb = L & 15, xb = L >> 4;                 // n-block (16), m-block (32): chunk 64 = 4 m x 16 n

  __shared__ u16 As[2][128 * 32];
  __shared__ u16 Bs[2][64 * 32];
  const int K = 1024, N = 1024;
  int tid = threadIdx.x;
  int lane = tid & 63, wave = tid >> 6;
  int quad = lane >> 4, c16 = lane & 15;
  int wm = wave >> 1, wn = wave & 1;            // wave tile 64x32
  int m0 = xb * 128, n0 = yb * 64;

  auto stageAB = [&](int k0, int bb) {
    #pragma unroll
    for (int i = 0; i < 2; i++) {                // A: 128 rows x 4 chunks = 512 chunks
      int slot = tid + i * 256;
      int r = slot >> 2, cc = (slot & 3) * 8;
      gload_lds16(&A[(size_t)(m0 + r) * K + k0 + cc], &As[bb][slot * 8]);
    }
    {                                            // B: 64 rows x 4 chunks = 256 chunks
      int r = tid >> 2, cc = (tid & 3) * 8;
      gload_lds16(&Wt[(size_t)(n0 + r) * K + k0 + cc], &Bs[bb][tid * 8]);
    }
  };

  f32x4 acc[4][2] = {};

  stageAB(0, 0);
  __syncthreads();                              // tile 0 ready

  for (int k0 = 0; k0 < K; k0 += 32) {
    int cb = (k0 >> 5) & 1;
    if (k0 + 32 < K) stageAB(k0 + 32, cb ^ 1);  // async prefetch, drained by end barrier
    bf16x8 af[4], bfr[2];
    #pragma unroll
    for (int mt = 0; mt < 4; mt++) af[mt]  = *(const bf16x8*)&As[cb][(wm * 64 + mt * 16 + c16) * 32 + quad * 8];
    #pragma unroll
    for (int nt = 0; nt < 2; nt++) bfr[nt] = *(const bf16x8*)&Bs[cb][(wn * 32 + nt * 16 + c16) * 32 + quad * 8];
    #pragma unroll
    for (int mt = 0; mt < 4; mt++)
      #pragma unroll
      for (int nt = 0; nt < 2; nt++)
        acc[mt][nt] = __builtin_amdgcn_mfma_f32_16x16x32_bf16(af[mt], bfr[nt], acc[mt][nt], 0, 0, 0);
    __syncthreads();
  }

  #pragma unroll
  for (int nt = 0; nt < 2; nt++) {
    int gc = n0 + wn * 32 + nt * 16 + c16;
    float bv = bias[gc];
    #pragma unroll
    for (int mt = 0; mt < 4; mt++)
      #pragma unroll
      for (int r = 0; r < 4; r++) {
        int gr = m0 + wm * 64 + mt * 16 + quad * 4 + r;
        C[(size_t)gr * N + gc] = acc[mt][nt][r] + bv;
      }
  }
}

// ---------------- flash attention: r6 structure (verified) + T1 XCD swizzle ----------------
// Swizzle: logical id qb-major within (b,h), so each XCD's 64-block chunk = 4 (b,h) pairs x 16 qb
// sharing K/V (512KB/pair) + Q (256KB/pair) in its private L2.
__global__ __launch_bounds__(256, 2) void k_attn(const u16* __restrict__ Qm,
                                                 const u16* __restrict__ Km,
                                                 const u16* __restrict__ VTm,
                                                 const float* __restrict__ mask,
                                                 u16* __restrict__ Om)
{
  __shared__ u16 KV[2][9216];        // [buf][K: 64x72 | VT: 64x72] (72 = 9 chunks of 16B)
  __shared__ float Msall[S_LEN];     // mask additive terms (pre-scaled by log2e), staged once
  const int NT = S_LEN / 64;
  int tid = threadIdx.x;
  int lane = tid & 63, wave = tid >> 6;         // wave 0..3
  int quad = lane >> 4, c16 = lane & 15;
  int wq = wave >> 1, wkv = wave & 1;           // q-half, kv-half

  int d = blockIdx.x + 16 * (blockIdx.y + 16 * blockIdx.z);
  int L = xcd_swz(d, 512);
  int qb = L & 15, h = (L >> 4) & 15, b = L >> 8;

  const size_t SH = (size_t)S_LEN * HDIM;
  const u16* Qbase  = Qm + (size_t)b * SH + (size_t)qb * 128 * HDIM + h * 64;
  const u16* Kbase  = Km + (size_t)b * SH + h * 64;
  const u16* VTbase = VTm + (size_t)(b * NHEAD + h) * 64 * S_LEN;
  const float* Mbase = mask + (size_t)b * S_LEN;

  auto stage = [&](int s0, int bb) {
    #pragma unroll
    for (int i = 0; i < 5; i++) {
      int c = i * 256 + tid;
      if (c < 576) {
        int r = c / 9, cc = c - r * 9;
        int col = (cc == 8) ? 0 : cc * 8;
        gload_lds16(&Kbase[(size_t)(s0 + r) * HDIM + col], &KV[bb][c * 8]);
      } else if (c < 1152) {
        int c2 = c - 576;
        int r = c2 / 9, cc = c2 - r * 9;
        int col = (cc == 8) ? 0 : cc * 8;
        gload_lds16(&VTbase[(size_t)r * S_LEN + s0 + col], &KV[bb][4608 + c2 * 8]);
      }
    }
  };

  stage(0, 0);
  for (int i = tid; i < S_LEN; i += 256) Msall[i] = (1.0f - Mbase[i]) * (-1.8033688e9f);  // (-1e10)/8*log2e

  int qw0 = wq * 64;                            // wave's 64 q-rows
  int kv0 = wkv * 32;                           // wave's 32-kv slice within each tile

  bf16x8 bq[4][2];
  #pragma unroll
  for (int qt = 0; qt < 4; qt++)
    #pragma unroll
    for (int kk = 0; kk < 2; kk++)
      bq[qt][kk] = *(const bf16x8*)&Qbase[(size_t)(qw0 + qt * 16 + c16) * HDIM + kk * 32 + quad * 8];

  f32x4 oacc[4][4] = {};       // D[q=qt*16+quad*4+r][d=dt*16+c16], partial over this wave's kv slices
  float lsq[4] = {};           // per-lane partial denominators for q = qt*16+c16

  __syncthreads();                              // tile 0 + Msall ready

  for (int kt = 0; kt < NT; kt++) {
    int s0 = kt * 64;
    int cb = kt & 1;
    const u16* Kb = &KV[cb][0];
    const u16* Vb = &KV[cb][4608];
    if (kt + 1 < NT) stage(s0 + 64, cb ^ 1);    // async prefetch, drained by end barrier

    f32x4 madd[2];
    #pragma unroll
    for (int kv2 = 0; kv2 < 2; kv2++) madd[kv2] = *(const f32x4*)&Msall[s0 + kv0 + kv2 * 16 + quad * 4];

    bf16x8 ak0[2], ak1[2];
    #pragma unroll
    for (int kv2 = 0; kv2 < 2; kv2++) {
      ak0[kv2] = *(const bf16x8*)&Kb[(kv0 + kv2 * 16 + c16) * 72 + quad * 8];
      ak1[kv2] = *(const bf16x8*)&Kb[(kv0 + kv2 * 16 + c16) * 72 + 32 + quad * 8];
    }
    f32x4 sacc[2][4];
    __builtin_amdgcn_s_setprio(1);
    #pragma unroll
    for (int kv2 = 0; kv2 < 2; kv2++)
      #pragma unroll
      for (int qt = 0; qt < 4; qt++)
        sacc[kv2][qt] = __builtin_amdgcn_mfma_f32_16x16x32_bf16(ak0[kv2], bq[qt][0], madd[kv2], 0, 0, 0);
    #pragma unroll
    for (int kv2 = 0; kv2 < 2; kv2++)
      #pragma unroll
      for (int qt = 0; qt < 4; qt++)
        sacc[kv2][qt] = __builtin_amdgcn_mfma_f32_16x16x32_bf16(ak1[kv2], bq[qt][1], sacc[kv2][qt], 0, 0, 0);
    __builtin_amdgcn_s_setprio(0);

    bf16x4 pa[4][2];
    #pragma unroll
    for (int kv2 = 0; kv2 < 2; kv2++)
      #pragma unroll
      for (int qt = 0; qt < 4; qt++) {
        float p0 = exp2_fast(sacc[kv2][qt][0]);
        float p1 = exp2_fast(sacc[kv2][qt][1]);
        float p2 = exp2_fast(sacc[kv2][qt][2]);
        float p3 = exp2_fast(sacc[kv2][qt][3]);
        lsq[qt] += (p0 + p1) + (p2 + p3);
        union { uint32_t u[2]; bf16x4 v; } cv;
        asm("v_cvt_pk_bf16_f32 %0, %1, %2" : "=v"(cv.u[0]) : "v"(p0), "v"(p1));
        asm("v_cvt_pk_bf16_f32 %0, %1, %2" : "=v"(cv.u[1]) : "v"(p2), "v"(p3));
        pa[qt][kv2] = cv.v;
      }

    __builtin_amdgcn_s_setprio(1);
    #pragma unroll
    for (int kv2 = 0; kv2 < 2; kv2++) {
      bf16x4 vb[4];
      #pragma unroll
      for (int dt = 0; dt < 4; dt++)
        vb[dt] = *(const bf16x4*)&Vb[(dt * 16 + c16) * 72 + kv0 + kv2 * 16 + quad * 4];
      #pragma unroll
      for (int qt = 0; qt < 4; qt++)
        #pragma unroll
        for (int dt = 0; dt < 4; dt++)
          oacc[qt][dt] = __builtin_amdgcn_mfma_f32_16x16x16bf16_1k(pa[qt][kv2], vb[dt], oacc[qt][dt], 0, 0, 0);
    }
    __builtin_amdgcn_s_setprio(0);
    __syncthreads();      // (a) all reads of buf cb done -> reusable; (b) vmcnt(0) drains prefetch
  }

  #pragma unroll
  for (int qt = 0; qt < 4; qt++) {
    float v = lsq[qt];
    v += __shfl_xor(v, 16);
    v += __shfl_xor(v, 32);
    lsq[qt] = v;
  }

  float* Osc = (float*)&KV[0][0];               // 2 x 16KB (per wq) <= 36864B
  float* Lsc = Msall;                           // 2 x 64 floats
  if (wkv == 1) {
    float* Ob = Osc + wq * 4096;
    #pragma unroll
    for (int qt = 0; qt < 4; qt++)
      #pragma unroll
      for (int dt = 0; dt < 4; dt++)
        #pragma unroll
        for (int r = 0; r < 4; r++)
          Ob[(qt * 16 + quad * 4 + r) * 64 + dt * 16 + c16] = oacc[qt][dt][r];
    if (lane < 16)
      #pragma unroll
      for (int qt = 0; qt < 4; qt++) Lsc[wq * 64 + qt * 16 + lane] = lsq[qt];
  }
  __syncthreads();
  if (wkv == 0) {
    float* Ob = Osc + wq * 4096;
    u16* Obase = Om + (size_t)b * SH + (size_t)qb * 128 * HDIM + h * 64;
    #pragma unroll
    for (int qt = 0; qt < 4; qt++)
      #pragma unroll
      for (int r = 0; r < 4; r++) {
        float l = __shfl(lsq[qt], quad * 4 + r) + Lsc[wq * 64 + qt * 16 + quad * 4 + r];
        float rinv = 1.0f / l;
        int lr = qw0 + qt * 16 + quad * 4 + r;
        #pragma unroll
        for (int dt = 0; dt < 4; dt++) {
          float o = oacc[qt][dt][r] + Ob[(qt * 16 + quad * 4 + r) * 64 + dt * 16 + c16];
          Obase[(size_t)lr * HDIM + dt * 16 + c16] = f2bf(o * rinv);
        }
      }
  }
}

extern "C" void kernel_launch(void* const* d_in, const int* in_sizes, int n_in,
                              void* d_out, int out_size, void* d_ws, size_t ws_size,
                              hipStream_t stream)
{
  (void)in_sizes; (void)n_in; (void)out_size; (void)ws_size;
  const float* q_in = (const float*)d_in[0];
  const float* k_in = (const float*)d_in[1];
  const float* v_in = (const float*)d_in[2];
  const float* mask = (const float*)d_in[3];
  const float* wq   = (const float*)d_in[4];
  const float* bq   = (const float*)d_in[5];
  const float* wk   = (const float*)d_in[6];
  const float* bk   = (const float*)d_in[7];
  const float* wv   = (const float*)d_in[8];
  const float* bv   = (const float*)d_in[9];
  const float* wo   = (const float*)d_in[10];
  const float* bo   = (const float*)d_in[11];

  u16* ws  = (u16*)d_ws;                 // bf16 elems: 4x1M wt + 3x4M in + 5x4M acts = 72 MB
  u16* wqt = ws;
  u16* wkt = wqt + (1u << 20);
  u16* wvt = wkt + (1u << 20);
  u16* wot = wvt + (1u << 20);
  u16* qi_ = wot + (1u << 20);
  u16* ki_ = qi_ + (4u << 20);
  u16* vi_ = ki_ + (4u << 20);
  u16* qb_ = vi_ + (4u << 20);
  u16* kb_ = qb_ + (4u << 20);
  u16* vb_ = kb_ + (4u << 20);
  u16* vtb = vb_ + (4u << 20);
  u16* ob_ = vtb + (4u << 20);

  dim3 blk(256);
  k_cvt3<<<dim3(2048, 3), blk, 0, stream>>>(q_in, k_in, v_in, qi_, ki_, vi_);
  k_tr_w4<<<dim3(16, 16, 4), blk, 0, stream>>>(wq, wk, wv, wo, wqt, wkt, wvt, wot);
  k_gemm_qkv<<<dim3(32, 8, 3), blk, 0, stream>>>(qi_, ki_, vi_, wqt, wkt, wvt, bq, bk, bv, qb_, kb_, vb_);
  k_tr_v<<<dim3(32, 32), blk, 0, stream>>>(vb_, vtb);
  k_attn<<<dim3(16, 16, 2), blk, 0, stream>>>(qb_, kb_, vtb, mask, ob_);
  k_gemm_o<<<dim3(32, 16), blk, 0, stream>>>(ob_, wot, bo, (float*)d_out);
}